// Round 10
// baseline (259.289 us; speedup 1.0000x reference)
//
#include <hip/hip_runtime.h>
#include <hip/hip_bf16.h>

#define NUM_USERS 60000
#define NUM_ITEMS 40000
#define NUM_NODES 100000
#define EMB 64
#define HID 32
#define N_EDGES 1600000
#define BATCH 16384

#define TILE 128           // nodes per bucket
#define NBUCK 782          // ceil(100000/128)
#define CAPB 3072          // padded bucket capacity (mean 2048 + row-pad <=128)
#define BLOCK_E 4096       // edges per partA block
#define NBLK_A 391         // ceil(1.6M/4096)
#define EPT 8              // edges per thread in partA (512 thr)
#define EPT_B (CAPB / 256) // 12

// workspace layout (u32 units):
//   CUR    @ 0       : 800       bucket write cursors (init b*CAPB)
//   BEND   @ 800     : 800       bucket end offsets (after partB)
//   ROFF   @ 1600    : 100352    CSR row starts (padded layout), 100001 used
//   BINNED @ 101952  : 4804608   782*3072 x uint2 {(row_local<<17)|col, val}
//   H1B    @ 4906560 : 1600000   100000 x 32 bf16
//   A1B    @ 6506560 : 1600000   100000 x 32 bf16
// peak 32.4 MB
#define WS_CUR    0
#define WS_BEND   800
#define WS_ROFF   1600
#define WS_BINNED 101952
#define WS_H1B    4906560
#define WS_A1B    6506560

// bf16 helpers (bit-exact, no API dependence)
static __device__ __forceinline__ unsigned short f2bf(float f) {
    union { float f; unsigned u; } x; x.f = f;
    unsigned u = x.u;
    return (unsigned short)((u + 0x7FFFu + ((u >> 16) & 1u)) >> 16);   // RNE
}
static __device__ __forceinline__ unsigned pack2bf(float lo, float hi) {
    return (unsigned)f2bf(lo) | ((unsigned)f2bf(hi) << 16);
}
static __device__ __forceinline__ float bflo(unsigned u) {
    union { unsigned v; float f; } x; x.v = u << 16; return x.f;
}
static __device__ __forceinline__ float bfhi(unsigned u) {
    union { unsigned v; float f; } x; x.v = u & 0xFFFF0000u; return x.f;
}

// ---------------------------------------------------------------------------
__global__ __launch_bounds__(1024) void k_initcur(unsigned* __restrict__ cur)
{
    int t = threadIdx.x;
    if (t < NBUCK) cur[t] = (unsigned)t * CAPB;
}

// ---------------------------------------------------------------------------
// Phase A: partition edges into 782 padded coarse buckets (LDS counting sort,
// global writes in contiguous spans).
// ---------------------------------------------------------------------------
__global__ __launch_bounds__(512) void k_partA(
    const int* __restrict__ rows, const int* __restrict__ cols,
    const float* __restrict__ vals,
    unsigned* __restrict__ cursor, uint2* __restrict__ binned)
{
    __shared__ unsigned cnt[NBUCK];
    __shared__ unsigned offs[NBUCK];
    __shared__ unsigned gbase[NBUCK];
    __shared__ unsigned scanbuf[1024];
    __shared__ uint2    staged[BLOCK_E];    // 32 KB
    __shared__ unsigned dstarr[BLOCK_E];    // 16 KB

    int t = threadIdx.x;
    for (int i = t; i < NBUCK; i += 512) cnt[i] = 0u;
    __syncthreads();

    unsigned eb = blockIdx.x * BLOCK_E;
    unsigned bb[EPT], rk[EPT];
    uint2    pr[EPT];
    #pragma unroll
    for (int i = 0; i < EPT; i++) {
        unsigned e = eb + (unsigned)(i * 512 + t);
        if (e < N_EDGES) {
            unsigned r = (unsigned)rows[e];
            bb[i] = r >> 7;
            pr[i] = make_uint2(((r & 127u) << 17) | (unsigned)cols[e],
                               __float_as_uint(vals[e]));
            rk[i] = atomicAdd(&cnt[bb[i]], 1u);
        } else {
            bb[i] = 0xFFFFFFFFu;
        }
    }
    __syncthreads();

    // exclusive scan of cnt -> offs (1024-wide Hillis-Steele, 2 elems/thread)
    unsigned c0 = (t < NBUCK) ? cnt[t] : 0u;
    unsigned c1 = (t + 512 < NBUCK) ? cnt[t + 512] : 0u;
    scanbuf[t] = c0; scanbuf[t + 512] = c1;
    __syncthreads();
    #pragma unroll
    for (int ofs = 1; ofs < 1024; ofs <<= 1) {
        unsigned a0 = (t >= ofs) ? scanbuf[t - ofs] : 0u;
        unsigned a1 = (t + 512 >= ofs) ? scanbuf[t + 512 - ofs] : 0u;
        __syncthreads();
        scanbuf[t] += a0; scanbuf[t + 512] += a1;
        __syncthreads();
    }
    if (t < NBUCK) offs[t] = scanbuf[t] - c0;
    if (t + 512 < NBUCK) offs[t + 512] = scanbuf[t + 512] - c1;
    __syncthreads();

    // reserve global spans (~782 low-contention atomics per block)
    for (int b = t; b < NBUCK; b += 512) {
        unsigned c = cnt[b];
        gbase[b] = c ? atomicAdd(&cursor[b], c) : 0u;
    }
    __syncthreads();

    // place into LDS bucket-sorted; record destination per slot
    #pragma unroll
    for (int i = 0; i < EPT; i++) {
        if (bb[i] != 0xFFFFFFFFu) {
            unsigned s = offs[bb[i]] + rk[i];
            staged[s] = pr[i];
            dstarr[s] = gbase[bb[i]] + rk[i];
        }
    }
    __syncthreads();

    unsigned total = (eb + BLOCK_E <= N_EDGES) ? (unsigned)BLOCK_E
                                               : (N_EDGES - eb);
    for (unsigned s = t; s < total; s += 512)
        binned[dstarr[s]] = staged[s];
}

// ---------------------------------------------------------------------------
// Phase B: counting-sort each padded bucket by row_local (in place), pad each
// row to EVEN length with {0,0} dummy edges (val=0 inert) so every row starts
// 16B-aligned; emit CSR row starts + bucket ends.  FUSED: computes layer-1
// dense H1B (bf16) for this bucket's 128 nodes (same FMA order as the old
// k_linear1 -> bit-identical).
// ---------------------------------------------------------------------------
__global__ __launch_bounds__(256) void k_partB(
    const unsigned* __restrict__ cursor,
    uint2* __restrict__ binned,
    unsigned* __restrict__ roff, unsigned* __restrict__ bend,
    const float* __restrict__ ue, const float* __restrict__ ie,
    const float* __restrict__ w1, const float* __restrict__ b1,
    unsigned* __restrict__ h1b)
{
    __shared__ uint2    ob[CAPB];      // 24 KB
    __shared__ unsigned cnt[TILE];
    __shared__ unsigned sc[TILE];
    __shared__ unsigned offs[TILE];
    __shared__ unsigned totpad;
    __shared__ float    ws1[HID * EMB];   // 8 KB
    __shared__ float    bs1[HID];

    int t = threadIdx.x;
    int nb = blockIdx.x;
    unsigned gs = (unsigned)nb * CAPB;
    unsigned count = cursor[nb] - gs;
    if (count > CAPB - TILE) count = CAPB - TILE;   // never trips

    for (int i = t; i < HID * EMB; i += 256) ws1[i] = w1[i];
    if (t < HID) bs1[t] = b1[t];
    for (int i = t; i < TILE; i += 256) cnt[i] = 0u;
    __syncthreads();

    unsigned rl_[EPT_B], rk_[EPT_B];
    uint2    pp_[EPT_B];
    #pragma unroll
    for (int it = 0; it < EPT_B; it++) {
        unsigned s = (unsigned)t + it * 256u;
        if (s < count) {
            uint2 p = binned[gs + s];
            unsigned rl = p.x >> 17;
            pp_[it] = p;
            rl_[it] = rl;
            rk_[it] = atomicAdd(&cnt[rl], 1u);
        } else {
            rl_[it] = 0xFFFFFFFFu;
        }
    }
    __syncthreads();

    // exclusive scan of even-padded row counts
    unsigned c  = (t < TILE) ? cnt[t] : 0u;
    unsigned pc = (c + 1u) & ~1u;
    if (t < TILE) sc[t] = pc;
    __syncthreads();
    #pragma unroll
    for (int ofs = 1; ofs < TILE; ofs <<= 1) {
        unsigned a = 0u;
        if (t < TILE && t >= ofs) a = sc[t - ofs];
        __syncthreads();
        if (t < TILE) sc[t] += a;
        __syncthreads();
    }
    if (t < TILE) offs[t] = sc[t] - pc;
    if (t == TILE - 1) totpad = sc[t];
    __syncthreads();

    // CSR row starts (even). nb=781,i=32 writes roff[100000]=bucket end.
    for (int i = t; i < TILE; i += 256) {
        int n = nb * TILE + i;
        if (n <= NUM_NODES) roff[n] = gs + offs[i];
    }
    if (t == 0) bend[nb] = gs + totpad;

    // dummy slot at end of odd-count rows
    if (t < TILE && (c & 1u)) ob[offs[t] + c] = make_uint2(0u, 0u);

    // place row-sorted into ob, then coalesced in-place write-back
    #pragma unroll
    for (int it = 0; it < EPT_B; it++) {
        if (rl_[it] != 0xFFFFFFFFu)
            ob[offs[rl_[it]] + rk_[it]] = pp_[it];
    }
    __syncthreads();
    unsigned tp = totpad;
    for (unsigned s = (unsigned)t; s < tp; s += 256)
        binned[gs + s] = ob[s];

    // ---- fused layer-1 dense for this bucket's nodes ----
    // 2 threads per node: thread t -> node (t&127), output half (t>>7)
    {
        int i = t & 127, h = t >> 7;
        int n = nb * TILE + i;
        if (n < NUM_NODES) {
            const float* row = (n < NUM_USERS)
                ? ue + (size_t)n * EMB
                : ie + (size_t)(n - NUM_USERS) * EMB;
            float x[EMB];
            #pragma unroll
            for (int k4 = 0; k4 < EMB / 4; k4++) {
                float4 v = reinterpret_cast<const float4*>(row)[k4];
                x[4*k4+0] = v.x; x[4*k4+1] = v.y;
                x[4*k4+2] = v.z; x[4*k4+3] = v.w;
            }
            const float4* ws4 = reinterpret_cast<const float4*>(ws1);
            float acc[16];
            #pragma unroll
            for (int jj = 0; jj < 16; jj++) {
                int j = h * 16 + jj;
                float a = bs1[j];
                #pragma unroll
                for (int k4 = 0; k4 < EMB / 4; k4++) {
                    float4 wv = ws4[j * (EMB/4) + k4];   // lane-uniform
                    a = fmaf(wv.x, x[4*k4+0], a);
                    a = fmaf(wv.y, x[4*k4+1], a);
                    a = fmaf(wv.z, x[4*k4+2], a);
                    a = fmaf(wv.w, x[4*k4+3], a);
                }
                acc[jj] = a;
            }
            uint4* o4 = reinterpret_cast<uint4*>(h1b + (size_t)n * 16 + h * 8);
            #pragma unroll
            for (int q8 = 0; q8 < 2; q8++) {
                uint4 o;
                o.x = pack2bf(acc[8*q8+0], acc[8*q8+1]);
                o.y = pack2bf(acc[8*q8+2], acc[8*q8+3]);
                o.z = pack2bf(acc[8*q8+4], acc[8*q8+5]);
                o.w = pack2bf(acc[8*q8+6], acc[8*q8+7]);
                o4[q8] = o;
            }
        }
    }
}

// ---------------------------------------------------------------------------
// CSR aggregation over 32-dim bf16 feature table, per-node wave, f32 register
// accumulate. Rows even-length & even-start: uint4 loads grab 2 edges.
// LAYER1: out = relu(agg) as bf16 table.
// !LAYER1 (fused layer-2): after butterfly every lane holds the FULL 32-dim
// aggregate + sumv; stage G in per-wave LDS, W2 in padded LDS (stride 33 ->
// (j+k)%32 banking, 2-way = free), each lane computes one of 64 outputs:
//   emb[n][j] = relu(sv*b2[j] + sum_k G[k]*W2[j][k])
// ---------------------------------------------------------------------------
template<bool LAYER1>
__global__ __launch_bounds__(256) void k_agg32(
    const unsigned* __restrict__ roff, const unsigned* __restrict__ bend,
    const uint2* __restrict__ binned,
    const unsigned* __restrict__ H,       // bf16 table, 16 u32 per row
    unsigned* __restrict__ outb,          // LAYER1: bf16 table out
    const float* __restrict__ w2, const float* __restrict__ b2,
    float* __restrict__ oute)             // !LAYER1: final f32 emb out
{
    __shared__ float w2s[EMB * 33];   // 8448 B (used only by !LAYER1)
    __shared__ float bs2[EMB];
    __shared__ float gbuf[4][32];

    int t = threadIdx.x;
    if (!LAYER1) {
        for (int idx = t; idx < EMB * HID; idx += 256) {
            int j = idx >> 5, k = idx & 31;
            w2s[j * 33 + k] = w2[idx];       // coalesced read, conflict-free wr
        }
        if (t < EMB) bs2[t] = b2[t];
    }

    int wave = t >> 6;
    int lane = t & 63;
    int n = blockIdx.x * 4 + wave;        // grid = NUM_NODES/4 exactly
    int g = lane >> 3;          // edge group 0..7
    int q = lane & 7;           // feature quad 0..7 (uint2 = 4 bf16)
    unsigned s = roff[n];
    unsigned e = ((n & 127) == 127) ? bend[n >> 7] : roff[n + 1];
    float4 acc = make_float4(0.f, 0.f, 0.f, 0.f);
    float sv = 0.f;
    for (unsigned k = s + 2u * (unsigned)g; k < e; k += 16u) {
        uint4 pp = *reinterpret_cast<const uint4*>(&binned[k]);   // 2 edges
        float va = __uint_as_float(pp.y);
        float vb = __uint_as_float(pp.w);
        uint2 ha = *(reinterpret_cast<const uint2*>(H + (size_t)(pp.x & 0x1FFFFu) * 16) + q);
        uint2 hb = *(reinterpret_cast<const uint2*>(H + (size_t)(pp.z & 0x1FFFFu) * 16) + q);
        acc.x = fmaf(va, bflo(ha.x), acc.x);
        acc.y = fmaf(va, bfhi(ha.x), acc.y);
        acc.z = fmaf(va, bflo(ha.y), acc.z);
        acc.w = fmaf(va, bfhi(ha.y), acc.w);
        acc.x = fmaf(vb, bflo(hb.x), acc.x);
        acc.y = fmaf(vb, bfhi(hb.x), acc.y);
        acc.z = fmaf(vb, bflo(hb.y), acc.z);
        acc.w = fmaf(vb, bfhi(hb.y), acc.w);
        if (!LAYER1) sv += va + vb;
    }
    #pragma unroll
    for (int m = 8; m < 64; m <<= 1) {    // butterfly: ALL lanes get totals
        acc.x += __shfl_xor(acc.x, m);
        acc.y += __shfl_xor(acc.y, m);
        acc.z += __shfl_xor(acc.z, m);
        acc.w += __shfl_xor(acc.w, m);
        if (!LAYER1) sv += __shfl_xor(sv, m);  // cross-group only: no dup
    }
    if (LAYER1) {
        if (g == 0) {
            acc.x = fmaxf(acc.x, 0.f); acc.y = fmaxf(acc.y, 0.f);
            acc.z = fmaxf(acc.z, 0.f); acc.w = fmaxf(acc.w, 0.f);
            uint2 o = make_uint2(pack2bf(acc.x, acc.y), pack2bf(acc.z, acc.w));
            *(reinterpret_cast<uint2*>(outb + (size_t)n * 16) + q) = o;
        }
    } else {
        if (g == 0) {
            gbuf[wave][q * 4 + 0] = acc.x;
            gbuf[wave][q * 4 + 1] = acc.y;
            gbuf[wave][q * 4 + 2] = acc.z;
            gbuf[wave][q * 4 + 3] = acc.w;
        }
        __syncthreads();    // gbuf + w2s/bs2 visible; no divergent returns
        float a = sv * bs2[lane];
        const float* wr = &w2s[lane * 33];
        const float* gb = gbuf[wave];
        #pragma unroll
        for (int k = 0; k < HID; k++)
            a = fmaf(gb[k], wr[k], a);     // gb: broadcast, wr: 2-way banked
        oute[(size_t)n * EMB + lane] = fmaxf(a, 0.f);   // 256B coalesced
    }
}

// ---------------------------------------------------------------------------
// MLP head: 32 threads per sample, 8 samples per block.
// ---------------------------------------------------------------------------
__global__ __launch_bounds__(256) void k_mlp(
    const int* __restrict__ uids, const int* __restrict__ iids,
    const float* __restrict__ uemb, const float* __restrict__ iemb,
    const float* __restrict__ p1w, const float* __restrict__ p1b,
    const float* __restrict__ p2w, const float* __restrict__ p2b,
    float* __restrict__ scores)
{
    __shared__ float w1t[2 * EMB * HID];   // [k4][j][4] packing
    __shared__ float zt[8][2 * EMB];
    __shared__ float b1s[HID];
    __shared__ float w2s[HID];

    for (int i = threadIdx.x; i < HID * 2 * EMB; i += 256) {
        int j = i >> 7;
        int k = i & 127;
        int k4 = k >> 2, c = k & 3;
        w1t[k4 * 128 + j * 4 + c] = p1w[i];
    }
    if (threadIdx.x < HID) {
        b1s[threadIdx.x] = p1b[threadIdx.x];
        w2s[threadIdx.x] = p2w[threadIdx.x];
    }
    __syncthreads();

    int lg = threadIdx.x >> 5;
    int j  = threadIdx.x & 31;
    int s  = blockIdx.x * 8 + lg;

    {
        int u  = uids[s];
        int it = iids[s];
        const float* bu = uemb + (size_t)u * EMB;
        const float* bi = iemb + (size_t)it * EMB;
        float* zs = zt[lg];
        zs[j]      = bu[j];
        zs[32 + j] = bu[32 + j];
        zs[64 + j] = bi[j];
        zs[96 + j] = bi[32 + j];
    }
    __syncthreads();

    const float*  zs = zt[lg];
    const float4* w4 = reinterpret_cast<const float4*>(w1t);
    const float4* z4 = reinterpret_cast<const float4*>(zs);
    float a = b1s[j];
    #pragma unroll
    for (int k4 = 0; k4 < 32; k4++) {
        float4 wv = w4[k4 * 32 + j];
        float4 zv = z4[k4];
        a = fmaf(wv.x, zv.x, a);
        a = fmaf(wv.y, zv.y, a);
        a = fmaf(wv.z, zv.z, a);
        a = fmaf(wv.w, zv.w, a);
    }
    a = fmaxf(a, 0.f);
    float part = a * w2s[j];
    #pragma unroll
    for (int m = 16; m >= 1; m >>= 1) part += __shfl_xor(part, m);
    if (j == 0) scores[s] = 1.f / (1.f + expf(-(part + p2b[0])));
}

// ---------------------------------------------------------------------------
extern "C" void kernel_launch(void* const* d_in, const int* in_sizes, int n_in,
                              void* d_out, int out_size, void* d_ws, size_t ws_size,
                              hipStream_t stream)
{
    const int*   user_ids = (const int*)  d_in[0];
    const int*   item_ids = (const int*)  d_in[1];
    const int*   adj_rows = (const int*)  d_in[2];
    const int*   adj_cols = (const int*)  d_in[3];
    const float* adj_vals = (const float*)d_in[4];
    const float* user_emb = (const float*)d_in[5];
    const float* item_emb = (const float*)d_in[6];
    const float* gc1_w    = (const float*)d_in[7];
    const float* gc1_b    = (const float*)d_in[8];
    const float* gc2_w    = (const float*)d_in[9];
    const float* gc2_b    = (const float*)d_in[10];
    const float* p1_w     = (const float*)d_in[11];
    const float* p1_b     = (const float*)d_in[12];
    const float* p2_w     = (const float*)d_in[13];
    const float* p2_b     = (const float*)d_in[14];

    float* out     = (float*)d_out;
    float* scores  = out;
    float* emb_out = out + BATCH;          // 100000*64 floats

    unsigned* ws_u   = (unsigned*)d_ws;
    unsigned* cur    = ws_u + WS_CUR;
    unsigned* bend   = ws_u + WS_BEND;
    unsigned* roff   = ws_u + WS_ROFF;
    uint2*    binned = (uint2*)(ws_u + WS_BINNED);
    unsigned* H1B    = ws_u + WS_H1B;
    unsigned* A1B    = ws_u + WS_A1B;

    // ---- partition + fused layer-1 linear ----
    k_initcur<<<1, 1024, 0, stream>>>(cur);
    k_partA<<<NBLK_A, 512, 0, stream>>>(adj_rows, adj_cols, adj_vals,
                                        cur, binned);
    k_partB<<<NBUCK, 256, 0, stream>>>(cur, binned, roff, bend,
                                       user_emb, item_emb, gc1_w, gc1_b, H1B);

    // ---- layer 1 aggregation (bf16 in, bf16 relu out) ----
    k_agg32<true><<<NUM_NODES / 4, 256, 0, stream>>>(
        roff, bend, binned, H1B, A1B, nullptr, nullptr, nullptr);

    // ---- layer 2 aggregation + fused linear (final embeddings) ----
    k_agg32<false><<<NUM_NODES / 4, 256, 0, stream>>>(
        roff, bend, binned, A1B, nullptr, gc2_w, gc2_b, emb_out);

    // ---- MLP head ----
    k_mlp<<<BATCH / 8, 256, 0, stream>>>(
        user_ids, item_ids, emb_out, emb_out + (size_t)NUM_USERS * EMB,
        p1_w, p1_b, p2_w, p2_b, scores);
}

// Round 13
// 255.033 us; speedup vs baseline: 1.0167x; 1.0167x over previous
//
#include <hip/hip_runtime.h>
#include <hip/hip_bf16.h>

#define NUM_USERS 60000
#define NUM_ITEMS 40000
#define NUM_NODES 100000
#define EMB 64
#define HID 32
#define N_EDGES 1600000
#define BATCH 16384

#define TILE 128           // nodes per bucket
#define NBUCK 782          // ceil(100000/128)
#define CAPB 3072          // padded bucket capacity (mean 2048 + row-pad <=128)
#define BLOCK_E 4096       // edges per partA block
#define NBLK_A 391         // ceil(1.6M/4096)
#define EPT 8              // edges per thread in partA (512 thr)
#define EPT_B (CAPB / 256) // 12

// clang ext vectors: valid operands for __builtin_nontemporal_{load,store}
typedef unsigned int u32x4 __attribute__((ext_vector_type(4)));
typedef unsigned int u32x2 __attribute__((ext_vector_type(2)));

// workspace layout (u32 units):
//   CUR    @ 0       : 800       bucket write cursors (init b*CAPB)
//   BEND   @ 800     : 800       bucket end offsets (after partB)
//   ROFF   @ 1600    : 100352    CSR row starts (padded layout), 100001 used
//   BINNED @ 101952  : 4804608   782*3072 x uint2 {(row_local<<17)|col, val}
//   H1B    @ 4906560 : 1600000   100000 x 32 bf16
//   A1B    @ 6506560 : 1600000   100000 x 32 bf16
// peak 32.4 MB
#define WS_CUR    0
#define WS_BEND   800
#define WS_ROFF   1600
#define WS_BINNED 101952
#define WS_H1B    4906560
#define WS_A1B    6506560

// bf16 helpers (bit-exact, no API dependence)
static __device__ __forceinline__ unsigned short f2bf(float f) {
    union { float f; unsigned u; } x; x.f = f;
    unsigned u = x.u;
    return (unsigned short)((u + 0x7FFFu + ((u >> 16) & 1u)) >> 16);   // RNE
}
static __device__ __forceinline__ unsigned pack2bf(float lo, float hi) {
    return (unsigned)f2bf(lo) | ((unsigned)f2bf(hi) << 16);
}
static __device__ __forceinline__ float bflo(unsigned u) {
    union { unsigned v; float f; } x; x.v = u << 16; return x.f;
}
static __device__ __forceinline__ float bfhi(unsigned u) {
    union { unsigned v; float f; } x; x.v = u & 0xFFFF0000u; return x.f;
}

// ---------------------------------------------------------------------------
__global__ __launch_bounds__(1024) void k_initcur(unsigned* __restrict__ cur)
{
    int t = threadIdx.x;
    if (t < NBUCK) cur[t] = (unsigned)t * CAPB;
}

// ---------------------------------------------------------------------------
// Phase A: partition edges into 782 padded coarse buckets (LDS counting sort,
// global writes in contiguous spans).
// ---------------------------------------------------------------------------
__global__ __launch_bounds__(512) void k_partA(
    const int* __restrict__ rows, const int* __restrict__ cols,
    const float* __restrict__ vals,
    unsigned* __restrict__ cursor, uint2* __restrict__ binned)
{
    __shared__ unsigned cnt[NBUCK];
    __shared__ unsigned offs[NBUCK];
    __shared__ unsigned gbase[NBUCK];
    __shared__ unsigned scanbuf[1024];
    __shared__ uint2    staged[BLOCK_E];    // 32 KB
    __shared__ unsigned dstarr[BLOCK_E];    // 16 KB

    int t = threadIdx.x;
    for (int i = t; i < NBUCK; i += 512) cnt[i] = 0u;
    __syncthreads();

    unsigned eb = blockIdx.x * BLOCK_E;
    unsigned bb[EPT], rk[EPT];
    uint2    pr[EPT];
    #pragma unroll
    for (int i = 0; i < EPT; i++) {
        unsigned e = eb + (unsigned)(i * 512 + t);
        if (e < N_EDGES) {
            unsigned r = (unsigned)rows[e];
            bb[i] = r >> 7;
            pr[i] = make_uint2(((r & 127u) << 17) | (unsigned)cols[e],
                               __float_as_uint(vals[e]));
            rk[i] = atomicAdd(&cnt[bb[i]], 1u);
        } else {
            bb[i] = 0xFFFFFFFFu;
        }
    }
    __syncthreads();

    // exclusive scan of cnt -> offs (1024-wide Hillis-Steele, 2 elems/thread)
    unsigned c0 = (t < NBUCK) ? cnt[t] : 0u;
    unsigned c1 = (t + 512 < NBUCK) ? cnt[t + 512] : 0u;
    scanbuf[t] = c0; scanbuf[t + 512] = c1;
    __syncthreads();
    #pragma unroll
    for (int ofs = 1; ofs < 1024; ofs <<= 1) {
        unsigned a0 = (t >= ofs) ? scanbuf[t - ofs] : 0u;
        unsigned a1 = (t + 512 >= ofs) ? scanbuf[t + 512 - ofs] : 0u;
        __syncthreads();
        scanbuf[t] += a0; scanbuf[t + 512] += a1;
        __syncthreads();
    }
    if (t < NBUCK) offs[t] = scanbuf[t] - c0;
    if (t + 512 < NBUCK) offs[t + 512] = scanbuf[t + 512] - c1;
    __syncthreads();

    // reserve global spans (~782 low-contention atomics per block)
    for (int b = t; b < NBUCK; b += 512) {
        unsigned c = cnt[b];
        gbase[b] = c ? atomicAdd(&cursor[b], c) : 0u;
    }
    __syncthreads();

    // place into LDS bucket-sorted; record destination per slot
    #pragma unroll
    for (int i = 0; i < EPT; i++) {
        if (bb[i] != 0xFFFFFFFFu) {
            unsigned s = offs[bb[i]] + rk[i];
            staged[s] = pr[i];
            dstarr[s] = gbase[bb[i]] + rk[i];
        }
    }
    __syncthreads();

    unsigned total = (eb + BLOCK_E <= N_EDGES) ? (unsigned)BLOCK_E
                                               : (N_EDGES - eb);
    for (unsigned s = t; s < total; s += 512)
        binned[dstarr[s]] = staged[s];
}

// ---------------------------------------------------------------------------
// Phase B: counting-sort each padded bucket by row_local (in place), pad each
// row to EVEN length with {0,0} dummy edges (val=0 inert) so every row starts
// 16B-aligned; emit CSR row starts + bucket ends.  FUSED: computes layer-1
// dense H1B (bf16) for this bucket's 128 nodes.
// ---------------------------------------------------------------------------
__global__ __launch_bounds__(256) void k_partB(
    const unsigned* __restrict__ cursor,
    uint2* __restrict__ binned,
    unsigned* __restrict__ roff, unsigned* __restrict__ bend,
    const float* __restrict__ ue, const float* __restrict__ ie,
    const float* __restrict__ w1, const float* __restrict__ b1,
    unsigned* __restrict__ h1b)
{
    __shared__ uint2    ob[CAPB];      // 24 KB
    __shared__ unsigned cnt[TILE];
    __shared__ unsigned sc[TILE];
    __shared__ unsigned offs[TILE];
    __shared__ unsigned totpad;
    __shared__ float    ws1[HID * EMB];   // 8 KB
    __shared__ float    bs1[HID];

    int t = threadIdx.x;
    int nb = blockIdx.x;
    unsigned gs = (unsigned)nb * CAPB;
    unsigned count = cursor[nb] - gs;
    if (count > CAPB - TILE) count = CAPB - TILE;   // never trips

    for (int i = t; i < HID * EMB; i += 256) ws1[i] = w1[i];
    if (t < HID) bs1[t] = b1[t];
    for (int i = t; i < TILE; i += 256) cnt[i] = 0u;
    __syncthreads();

    unsigned rl_[EPT_B], rk_[EPT_B];
    uint2    pp_[EPT_B];
    #pragma unroll
    for (int it = 0; it < EPT_B; it++) {
        unsigned s = (unsigned)t + it * 256u;
        if (s < count) {
            uint2 p = binned[gs + s];
            unsigned rl = p.x >> 17;
            pp_[it] = p;
            rl_[it] = rl;
            rk_[it] = atomicAdd(&cnt[rl], 1u);
        } else {
            rl_[it] = 0xFFFFFFFFu;
        }
    }
    __syncthreads();

    // exclusive scan of even-padded row counts
    unsigned c  = (t < TILE) ? cnt[t] : 0u;
    unsigned pc = (c + 1u) & ~1u;
    if (t < TILE) sc[t] = pc;
    __syncthreads();
    #pragma unroll
    for (int ofs = 1; ofs < TILE; ofs <<= 1) {
        unsigned a = 0u;
        if (t < TILE && t >= ofs) a = sc[t - ofs];
        __syncthreads();
        if (t < TILE) sc[t] += a;
        __syncthreads();
    }
    if (t < TILE) offs[t] = sc[t] - pc;
    if (t == TILE - 1) totpad = sc[t];
    __syncthreads();

    // CSR row starts (even). nb=781,i=32 writes roff[100000]=bucket end.
    for (int i = t; i < TILE; i += 256) {
        int n = nb * TILE + i;
        if (n <= NUM_NODES) roff[n] = gs + offs[i];
    }
    if (t == 0) bend[nb] = gs + totpad;

    // dummy slot at end of odd-count rows
    if (t < TILE && (c & 1u)) ob[offs[t] + c] = make_uint2(0u, 0u);

    // place row-sorted into ob, then coalesced in-place write-back
    #pragma unroll
    for (int it = 0; it < EPT_B; it++) {
        if (rl_[it] != 0xFFFFFFFFu)
            ob[offs[rl_[it]] + rk_[it]] = pp_[it];
    }
    __syncthreads();
    unsigned tp = totpad;
    for (unsigned s = (unsigned)t; s < tp; s += 256)
        binned[gs + s] = ob[s];

    // ---- fused layer-1 dense for this bucket's nodes ----
    // 2 threads per node: thread t -> node (t&127), output half (t>>7)
    {
        int i = t & 127, h = t >> 7;
        int n = nb * TILE + i;
        if (n < NUM_NODES) {
            const float* row = (n < NUM_USERS)
                ? ue + (size_t)n * EMB
                : ie + (size_t)(n - NUM_USERS) * EMB;
            float x[EMB];
            #pragma unroll
            for (int k4 = 0; k4 < EMB / 4; k4++) {
                float4 v = reinterpret_cast<const float4*>(row)[k4];
                x[4*k4+0] = v.x; x[4*k4+1] = v.y;
                x[4*k4+2] = v.z; x[4*k4+3] = v.w;
            }
            const float4* ws4 = reinterpret_cast<const float4*>(ws1);
            float acc[16];
            #pragma unroll
            for (int jj = 0; jj < 16; jj++) {
                int j = h * 16 + jj;
                float a = bs1[j];
                #pragma unroll
                for (int k4 = 0; k4 < EMB / 4; k4++) {
                    float4 wv = ws4[j * (EMB/4) + k4];   // lane-uniform
                    a = fmaf(wv.x, x[4*k4+0], a);
                    a = fmaf(wv.y, x[4*k4+1], a);
                    a = fmaf(wv.z, x[4*k4+2], a);
                    a = fmaf(wv.w, x[4*k4+3], a);
                }
                acc[jj] = a;
            }
            uint4* o4 = reinterpret_cast<uint4*>(h1b + (size_t)n * 16 + h * 8);
            #pragma unroll
            for (int q8 = 0; q8 < 2; q8++) {
                uint4 o;
                o.x = pack2bf(acc[8*q8+0], acc[8*q8+1]);
                o.y = pack2bf(acc[8*q8+2], acc[8*q8+3]);
                o.z = pack2bf(acc[8*q8+4], acc[8*q8+5]);
                o.w = pack2bf(acc[8*q8+6], acc[8*q8+7]);
                o4[q8] = o;
            }
        }
    }
}

// ---------------------------------------------------------------------------
// CSR aggregation, 2 NODES PER WAVE (latency-wall amortization): both nodes'
// roff/pair/H load chains are independent -> in flight together. First chunk
// (16 edges = mean degree) is straight-line predicated; rare tail loops after.
// FMA order per node identical to the single-node version -> bit-identical.
// LAYER1: out = relu(agg) bf16.  !LAYER1: fused layer-2 linear epilogue,
// per-wave gbuf (no block barrier; W2 staged at top with one early barrier).
// ---------------------------------------------------------------------------
template<bool LAYER1>
__global__ __launch_bounds__(256) void k_agg32(
    const unsigned* __restrict__ roff, const unsigned* __restrict__ bend,
    const uint2* __restrict__ binned,
    const unsigned* __restrict__ H,       // bf16 table, 16 u32 per row
    unsigned* __restrict__ outb,          // LAYER1: bf16 table out
    const float* __restrict__ w2, const float* __restrict__ b2,
    float* __restrict__ oute)             // !LAYER1: final f32 emb out
{
    __shared__ float w2s[EMB * 33];   // (only used by !LAYER1; LDS not binding)
    __shared__ float bs2[EMB];
    __shared__ float gbuf[4][2][32];

    int t = threadIdx.x;
    if (!LAYER1) {
        for (int idx = t; idx < EMB * HID; idx += 256) {
            int j = idx >> 5, k = idx & 31;
            w2s[j * 33 + k] = w2[idx];
        }
        if (t < EMB) bs2[t] = b2[t];
        __syncthreads();   // once, early: all staging visible before epilogue
    }

    int wave = t >> 6;
    int lane = t & 63;
    int g = lane >> 3;          // edge group 0..7
    int q = lane & 7;           // feature quad 0..7 (u32x2 = 4 bf16)
    int n0 = blockIdx.x * 8 + wave * 2;   // grid = NUM_NODES/8 exactly
    int n1 = n0 + 1;
    unsigned s0 = roff[n0];
    unsigned s1 = roff[n1];               // n0 even -> same bucket; e0 == s1
    unsigned e0 = s1;
    unsigned e1 = ((n1 & 127) == 127) ? bend[n1 >> 7] : roff[n1 + 1];

    float4 acc0 = make_float4(0.f, 0.f, 0.f, 0.f);
    float4 acc1 = make_float4(0.f, 0.f, 0.f, 0.f);
    float sv0 = 0.f, sv1 = 0.f;

    // ---- first chunk, both nodes: loads batched, chains overlap ----
    unsigned k0 = s0 + 2u * (unsigned)g;
    unsigned k1 = s1 + 2u * (unsigned)g;
    u32x4 P0 = (u32x4){0u, 0u, 0u, 0u};
    u32x4 P1 = (u32x4){0u, 0u, 0u, 0u};
    // rows are even-length: k<e implies both edges of the 16B load valid
    if (k0 < e0) P0 = __builtin_nontemporal_load(
        reinterpret_cast<const u32x4*>(&binned[k0]));
    if (k1 < e1) P1 = __builtin_nontemporal_load(
        reinterpret_cast<const u32x4*>(&binned[k1]));
    // inactive lanes read H row 0 (broadcast line) with v=0 -> inert
    {
        uint2 ha0 = *(reinterpret_cast<const uint2*>(H + (size_t)(P0.x & 0x1FFFFu) * 16) + q);
        uint2 hb0 = *(reinterpret_cast<const uint2*>(H + (size_t)(P0.z & 0x1FFFFu) * 16) + q);
        uint2 ha1 = *(reinterpret_cast<const uint2*>(H + (size_t)(P1.x & 0x1FFFFu) * 16) + q);
        uint2 hb1 = *(reinterpret_cast<const uint2*>(H + (size_t)(P1.z & 0x1FFFFu) * 16) + q);
        float va0 = __uint_as_float(P0.y), vb0 = __uint_as_float(P0.w);
        float va1 = __uint_as_float(P1.y), vb1 = __uint_as_float(P1.w);
        acc0.x = fmaf(va0, bflo(ha0.x), acc0.x);
        acc0.y = fmaf(va0, bfhi(ha0.x), acc0.y);
        acc0.z = fmaf(va0, bflo(ha0.y), acc0.z);
        acc0.w = fmaf(va0, bfhi(ha0.y), acc0.w);
        acc0.x = fmaf(vb0, bflo(hb0.x), acc0.x);
        acc0.y = fmaf(vb0, bfhi(hb0.x), acc0.y);
        acc0.z = fmaf(vb0, bflo(hb0.y), acc0.z);
        acc0.w = fmaf(vb0, bfhi(hb0.y), acc0.w);
        acc1.x = fmaf(va1, bflo(ha1.x), acc1.x);
        acc1.y = fmaf(va1, bfhi(ha1.x), acc1.y);
        acc1.z = fmaf(va1, bflo(ha1.y), acc1.z);
        acc1.w = fmaf(va1, bfhi(ha1.y), acc1.w);
        acc1.x = fmaf(vb1, bflo(hb1.x), acc1.x);
        acc1.y = fmaf(vb1, bfhi(hb1.x), acc1.y);
        acc1.z = fmaf(vb1, bflo(hb1.y), acc1.z);
        acc1.w = fmaf(vb1, bfhi(hb1.y), acc1.w);
        if (!LAYER1) { sv0 += va0 + vb0; sv1 += va1 + vb1; }
    }
    // ---- tails (entered ~46% of rows; Poisson(16)) ----
    for (unsigned k = k0 + 16u; k < e0; k += 16u) {
        u32x4 pp = __builtin_nontemporal_load(
            reinterpret_cast<const u32x4*>(&binned[k]));
        float va = __uint_as_float(pp.y), vb = __uint_as_float(pp.w);
        uint2 ha = *(reinterpret_cast<const uint2*>(H + (size_t)(pp.x & 0x1FFFFu) * 16) + q);
        uint2 hb = *(reinterpret_cast<const uint2*>(H + (size_t)(pp.z & 0x1FFFFu) * 16) + q);
        acc0.x = fmaf(va, bflo(ha.x), acc0.x);
        acc0.y = fmaf(va, bfhi(ha.x), acc0.y);
        acc0.z = fmaf(va, bflo(ha.y), acc0.z);
        acc0.w = fmaf(va, bfhi(ha.y), acc0.w);
        acc0.x = fmaf(vb, bflo(hb.x), acc0.x);
        acc0.y = fmaf(vb, bfhi(hb.x), acc0.y);
        acc0.z = fmaf(vb, bflo(hb.y), acc0.z);
        acc0.w = fmaf(vb, bfhi(hb.y), acc0.w);
        if (!LAYER1) sv0 += va + vb;
    }
    for (unsigned k = k1 + 16u; k < e1; k += 16u) {
        u32x4 pp = __builtin_nontemporal_load(
            reinterpret_cast<const u32x4*>(&binned[k]));
        float va = __uint_as_float(pp.y), vb = __uint_as_float(pp.w);
        uint2 ha = *(reinterpret_cast<const uint2*>(H + (size_t)(pp.x & 0x1FFFFu) * 16) + q);
        uint2 hb = *(reinterpret_cast<const uint2*>(H + (size_t)(pp.z & 0x1FFFFu) * 16) + q);
        acc1.x = fmaf(va, bflo(ha.x), acc1.x);
        acc1.y = fmaf(va, bfhi(ha.x), acc1.y);
        acc1.z = fmaf(va, bflo(ha.y), acc1.z);
        acc1.w = fmaf(va, bfhi(ha.y), acc1.w);
        acc1.x = fmaf(vb, bflo(hb.x), acc1.x);
        acc1.y = fmaf(vb, bfhi(hb.x), acc1.y);
        acc1.z = fmaf(vb, bflo(hb.y), acc1.z);
        acc1.w = fmaf(vb, bfhi(hb.y), acc1.w);
        if (!LAYER1) sv1 += va + vb;
    }

    #pragma unroll
    for (int m = 8; m < 64; m <<= 1) {    // cross-group butterfly (all lanes)
        acc0.x += __shfl_xor(acc0.x, m);
        acc0.y += __shfl_xor(acc0.y, m);
        acc0.z += __shfl_xor(acc0.z, m);
        acc0.w += __shfl_xor(acc0.w, m);
        acc1.x += __shfl_xor(acc1.x, m);
        acc1.y += __shfl_xor(acc1.y, m);
        acc1.z += __shfl_xor(acc1.z, m);
        acc1.w += __shfl_xor(acc1.w, m);
        if (!LAYER1) { sv0 += __shfl_xor(sv0, m); sv1 += __shfl_xor(sv1, m); }
    }

    if (LAYER1) {
        if (g == 0) {
            acc0.x = fmaxf(acc0.x, 0.f); acc0.y = fmaxf(acc0.y, 0.f);
            acc0.z = fmaxf(acc0.z, 0.f); acc0.w = fmaxf(acc0.w, 0.f);
            acc1.x = fmaxf(acc1.x, 0.f); acc1.y = fmaxf(acc1.y, 0.f);
            acc1.z = fmaxf(acc1.z, 0.f); acc1.w = fmaxf(acc1.w, 0.f);
            u32x2 o0 = (u32x2){pack2bf(acc0.x, acc0.y), pack2bf(acc0.z, acc0.w)};
            u32x2 o1 = (u32x2){pack2bf(acc1.x, acc1.y), pack2bf(acc1.z, acc1.w)};
            __builtin_nontemporal_store(o0,
                reinterpret_cast<u32x2*>(outb + (size_t)n0 * 16) + q);
            __builtin_nontemporal_store(o1,
                reinterpret_cast<u32x2*>(outb + (size_t)n1 * 16) + q);
        }
    } else {
        if (g == 0) {
            gbuf[wave][0][q * 4 + 0] = acc0.x;
            gbuf[wave][0][q * 4 + 1] = acc0.y;
            gbuf[wave][0][q * 4 + 2] = acc0.z;
            gbuf[wave][0][q * 4 + 3] = acc0.w;
            gbuf[wave][1][q * 4 + 0] = acc1.x;
            gbuf[wave][1][q * 4 + 1] = acc1.y;
            gbuf[wave][1][q * 4 + 2] = acc1.z;
            gbuf[wave][1][q * 4 + 3] = acc1.w;
        }
        // same-wave LDS RAW: compiler inserts lgkmcnt wait; no barrier needed
        float a0 = sv0 * bs2[lane];
        float a1 = sv1 * bs2[lane];
        const float* wr = &w2s[lane * 33];   // (lane+k)%32 banking: 2-way, free
        const float* g0 = gbuf[wave][0];     // broadcast
        const float* g1 = gbuf[wave][1];
        #pragma unroll
        for (int k = 0; k < HID; k++) {
            a0 = fmaf(g0[k], wr[k], a0);
            a1 = fmaf(g1[k], wr[k], a1);
        }
        __builtin_nontemporal_store(fmaxf(a0, 0.f),
                                    &oute[(size_t)n0 * EMB + lane]);
        __builtin_nontemporal_store(fmaxf(a1, 0.f),
                                    &oute[(size_t)n1 * EMB + lane]);
    }
}

// ---------------------------------------------------------------------------
// MLP head: 32 threads per sample, 8 samples per block.
// ---------------------------------------------------------------------------
__global__ __launch_bounds__(256) void k_mlp(
    const int* __restrict__ uids, const int* __restrict__ iids,
    const float* __restrict__ uemb, const float* __restrict__ iemb,
    const float* __restrict__ p1w, const float* __restrict__ p1b,
    const float* __restrict__ p2w, const float* __restrict__ p2b,
    float* __restrict__ scores)
{
    __shared__ float w1t[2 * EMB * HID];   // [k4][j][4] packing
    __shared__ float zt[8][2 * EMB];
    __shared__ float b1s[HID];
    __shared__ float w2s[HID];

    for (int i = threadIdx.x; i < HID * 2 * EMB; i += 256) {
        int j = i >> 7;
        int k = i & 127;
        int k4 = k >> 2, c = k & 3;
        w1t[k4 * 128 + j * 4 + c] = p1w[i];
    }
    if (threadIdx.x < HID) {
        b1s[threadIdx.x] = p1b[threadIdx.x];
        w2s[threadIdx.x] = p2w[threadIdx.x];
    }
    __syncthreads();

    int lg = threadIdx.x >> 5;
    int j  = threadIdx.x & 31;
    int s  = blockIdx.x * 8 + lg;

    {
        int u  = uids[s];
        int it = iids[s];
        const float* bu = uemb + (size_t)u * EMB;
        const float* bi = iemb + (size_t)it * EMB;
        float* zs = zt[lg];
        zs[j]      = bu[j];
        zs[32 + j] = bu[32 + j];
        zs[64 + j] = bi[j];
        zs[96 + j] = bi[32 + j];
    }
    __syncthreads();

    const float*  zs = zt[lg];
    const float4* w4 = reinterpret_cast<const float4*>(w1t);
    const float4* z4 = reinterpret_cast<const float4*>(zs);
    float a = b1s[j];
    #pragma unroll
    for (int k4 = 0; k4 < 32; k4++) {
        float4 wv = w4[k4 * 32 + j];
        float4 zv = z4[k4];
        a = fmaf(wv.x, zv.x, a);
        a = fmaf(wv.y, zv.y, a);
        a = fmaf(wv.z, zv.z, a);
        a = fmaf(wv.w, zv.w, a);
    }
    a = fmaxf(a, 0.f);
    float part = a * w2s[j];
    #pragma unroll
    for (int m = 16; m >= 1; m >>= 1) part += __shfl_xor(part, m);
    if (j == 0) scores[s] = 1.f / (1.f + expf(-(part + p2b[0])));
}

// ---------------------------------------------------------------------------
extern "C" void kernel_launch(void* const* d_in, const int* in_sizes, int n_in,
                              void* d_out, int out_size, void* d_ws, size_t ws_size,
                              hipStream_t stream)
{
    const int*   user_ids = (const int*)  d_in[0];
    const int*   item_ids = (const int*)  d_in[1];
    const int*   adj_rows = (const int*)  d_in[2];
    const int*   adj_cols = (const int*)  d_in[3];
    const float* adj_vals = (const float*)d_in[4];
    const float* user_emb = (const float*)d_in[5];
    const float* item_emb = (const float*)d_in[6];
    const float* gc1_w    = (const float*)d_in[7];
    const float* gc1_b    = (const float*)d_in[8];
    const float* gc2_w    = (const float*)d_in[9];
    const float* gc2_b    = (const float*)d_in[10];
    const float* p1_w     = (const float*)d_in[11];
    const float* p1_b     = (const float*)d_in[12];
    const float* p2_w     = (const float*)d_in[13];
    const float* p2_b     = (const float*)d_in[14];

    float* out     = (float*)d_out;
    float* scores  = out;
    float* emb_out = out + BATCH;          // 100000*64 floats

    unsigned* ws_u   = (unsigned*)d_ws;
    unsigned* cur    = ws_u + WS_CUR;
    unsigned* bend   = ws_u + WS_BEND;
    unsigned* roff   = ws_u + WS_ROFF;
    uint2*    binned = (uint2*)(ws_u + WS_BINNED);
    unsigned* H1B    = ws_u + WS_H1B;
    unsigned* A1B    = ws_u + WS_A1B;

    // ---- partition + fused layer-1 linear ----
    k_initcur<<<1, 1024, 0, stream>>>(cur);
    k_partA<<<NBLK_A, 512, 0, stream>>>(adj_rows, adj_cols, adj_vals,
                                        cur, binned);
    k_partB<<<NBUCK, 256, 0, stream>>>(cur, binned, roff, bend,
                                       user_emb, item_emb, gc1_w, gc1_b, H1B);

    // ---- layer 1 aggregation (bf16 in, bf16 relu out), 8 nodes/block ----
    k_agg32<true><<<NUM_NODES / 8, 256, 0, stream>>>(
        roff, bend, binned, H1B, A1B, nullptr, nullptr, nullptr);

    // ---- layer 2 aggregation + fused linear (final embeddings) ----
    k_agg32<false><<<NUM_NODES / 8, 256, 0, stream>>>(
        roff, bend, binned, A1B, nullptr, gc2_w, gc2_b, emb_out);

    // ---- MLP head ----
    k_mlp<<<BATCH / 8, 256, 0, stream>>>(
        user_ids, item_ids, emb_out, emb_out + (size_t)NUM_USERS * EMB,
        p1_w, p1_b, p2_w, p2_b, scores);
}

// Round 14
// 247.845 us; speedup vs baseline: 1.0462x; 1.0290x over previous
//
#include <hip/hip_runtime.h>
#include <hip/hip_bf16.h>

#define NUM_USERS 60000
#define NUM_ITEMS 40000
#define NUM_NODES 100000
#define EMB 64
#define HID 32
#define N_EDGES 1600000
#define BATCH 16384

#define TILE 128           // nodes per bucket
#define NBUCK 782          // ceil(100000/128)
#define CAPB 3072          // padded bucket capacity (mean 2048 + row-pad <=128)
#define BLOCK_E 4096       // edges per partA block
#define NBLK_A 391         // ceil(1.6M/4096)
#define EPT 8              // edges per thread in partA (512 thr)
#define EPT_B (CAPB / 256) // 12

// clang ext vectors: valid operands for __builtin_nontemporal_{load,store}
typedef unsigned int u32x4 __attribute__((ext_vector_type(4)));
typedef unsigned int u32x2 __attribute__((ext_vector_type(2)));

// workspace layout (u32 units):
//   CUR    @ 0       : 800       bucket write cursors (init b*CAPB)
//   BEND   @ 800     : 800       bucket end offsets (after partB)
//   ROFF   @ 1600    : 100352    CSR row starts (padded layout), 100001 used
//   BINNED @ 101952  : 4804608   782*3072 x uint2 {(row_local<<17)|col, val}
//   H1B    @ 4906560 : 1600000   100000 x 32 bf16
//   A1B    @ 6506560 : 1600000   100000 x 32 bf16
// peak 32.4 MB
#define WS_CUR    0
#define WS_BEND   800
#define WS_ROFF   1600
#define WS_BINNED 101952
#define WS_H1B    4906560
#define WS_A1B    6506560

// bf16 helpers (bit-exact, no API dependence)
static __device__ __forceinline__ unsigned short f2bf(float f) {
    union { float f; unsigned u; } x; x.f = f;
    unsigned u = x.u;
    return (unsigned short)((u + 0x7FFFu + ((u >> 16) & 1u)) >> 16);   // RNE
}
static __device__ __forceinline__ unsigned pack2bf(float lo, float hi) {
    return (unsigned)f2bf(lo) | ((unsigned)f2bf(hi) << 16);
}
static __device__ __forceinline__ float bflo(unsigned u) {
    union { unsigned v; float f; } x; x.v = u << 16; return x.f;
}
static __device__ __forceinline__ float bfhi(unsigned u) {
    union { unsigned v; float f; } x; x.v = u & 0xFFFF0000u; return x.f;
}

// ---------------------------------------------------------------------------
__global__ __launch_bounds__(1024) void k_initcur(unsigned* __restrict__ cur)
{
    int t = threadIdx.x;
    if (t < NBUCK) cur[t] = (unsigned)t * CAPB;
}

// ---------------------------------------------------------------------------
// Phase A: partition edges into 782 padded coarse buckets (LDS counting sort,
// global writes in contiguous spans).
// ---------------------------------------------------------------------------
__global__ __launch_bounds__(512) void k_partA(
    const int* __restrict__ rows, const int* __restrict__ cols,
    const float* __restrict__ vals,
    unsigned* __restrict__ cursor, uint2* __restrict__ binned)
{
    __shared__ unsigned cnt[NBUCK];
    __shared__ unsigned offs[NBUCK];
    __shared__ unsigned gbase[NBUCK];
    __shared__ unsigned scanbuf[1024];
    __shared__ uint2    staged[BLOCK_E];    // 32 KB
    __shared__ unsigned dstarr[BLOCK_E];    // 16 KB

    int t = threadIdx.x;
    for (int i = t; i < NBUCK; i += 512) cnt[i] = 0u;
    __syncthreads();

    unsigned eb = blockIdx.x * BLOCK_E;
    unsigned bb[EPT], rk[EPT];
    uint2    pr[EPT];
    #pragma unroll
    for (int i = 0; i < EPT; i++) {
        unsigned e = eb + (unsigned)(i * 512 + t);
        if (e < N_EDGES) {
            unsigned r = (unsigned)rows[e];
            bb[i] = r >> 7;
            pr[i] = make_uint2(((r & 127u) << 17) | (unsigned)cols[e],
                               __float_as_uint(vals[e]));
            rk[i] = atomicAdd(&cnt[bb[i]], 1u);
        } else {
            bb[i] = 0xFFFFFFFFu;
        }
    }
    __syncthreads();

    // exclusive scan of cnt -> offs (1024-wide Hillis-Steele, 2 elems/thread)
    unsigned c0 = (t < NBUCK) ? cnt[t] : 0u;
    unsigned c1 = (t + 512 < NBUCK) ? cnt[t + 512] : 0u;
    scanbuf[t] = c0; scanbuf[t + 512] = c1;
    __syncthreads();
    #pragma unroll
    for (int ofs = 1; ofs < 1024; ofs <<= 1) {
        unsigned a0 = (t >= ofs) ? scanbuf[t - ofs] : 0u;
        unsigned a1 = (t + 512 >= ofs) ? scanbuf[t + 512 - ofs] : 0u;
        __syncthreads();
        scanbuf[t] += a0; scanbuf[t + 512] += a1;
        __syncthreads();
    }
    if (t < NBUCK) offs[t] = scanbuf[t] - c0;
    if (t + 512 < NBUCK) offs[t + 512] = scanbuf[t + 512] - c1;
    __syncthreads();

    // reserve global spans (~782 low-contention atomics per block)
    for (int b = t; b < NBUCK; b += 512) {
        unsigned c = cnt[b];
        gbase[b] = c ? atomicAdd(&cursor[b], c) : 0u;
    }
    __syncthreads();

    // place into LDS bucket-sorted; record destination per slot
    #pragma unroll
    for (int i = 0; i < EPT; i++) {
        if (bb[i] != 0xFFFFFFFFu) {
            unsigned s = offs[bb[i]] + rk[i];
            staged[s] = pr[i];
            dstarr[s] = gbase[bb[i]] + rk[i];
        }
    }
    __syncthreads();

    unsigned total = (eb + BLOCK_E <= N_EDGES) ? (unsigned)BLOCK_E
                                               : (N_EDGES - eb);
    for (unsigned s = t; s < total; s += 512)
        binned[dstarr[s]] = staged[s];
}

// ---------------------------------------------------------------------------
// Phase B: counting-sort each padded bucket by row_local (in place), pad each
// row to EVEN length with {0,0} dummy edges (val=0 inert) so every row starts
// 16B-aligned; emit CSR row starts + bucket ends.  FUSED: computes layer-1
// dense H1B (bf16) for this bucket's 128 nodes.
// ---------------------------------------------------------------------------
__global__ __launch_bounds__(256) void k_partB(
    const unsigned* __restrict__ cursor,
    uint2* __restrict__ binned,
    unsigned* __restrict__ roff, unsigned* __restrict__ bend,
    const float* __restrict__ ue, const float* __restrict__ ie,
    const float* __restrict__ w1, const float* __restrict__ b1,
    unsigned* __restrict__ h1b)
{
    __shared__ uint2    ob[CAPB];      // 24 KB
    __shared__ unsigned cnt[TILE];
    __shared__ unsigned sc[TILE];
    __shared__ unsigned offs[TILE];
    __shared__ unsigned totpad;
    __shared__ float    ws1[HID * EMB];   // 8 KB
    __shared__ float    bs1[HID];

    int t = threadIdx.x;
    int nb = blockIdx.x;
    unsigned gs = (unsigned)nb * CAPB;
    unsigned count = cursor[nb] - gs;
    if (count > CAPB - TILE) count = CAPB - TILE;   // never trips

    for (int i = t; i < HID * EMB; i += 256) ws1[i] = w1[i];
    if (t < HID) bs1[t] = b1[t];
    for (int i = t; i < TILE; i += 256) cnt[i] = 0u;
    __syncthreads();

    unsigned rl_[EPT_B], rk_[EPT_B];
    uint2    pp_[EPT_B];
    #pragma unroll
    for (int it = 0; it < EPT_B; it++) {
        unsigned s = (unsigned)t + it * 256u;
        if (s < count) {
            uint2 p = binned[gs + s];
            unsigned rl = p.x >> 17;
            pp_[it] = p;
            rl_[it] = rl;
            rk_[it] = atomicAdd(&cnt[rl], 1u);
        } else {
            rl_[it] = 0xFFFFFFFFu;
        }
    }
    __syncthreads();

    // exclusive scan of even-padded row counts
    unsigned c  = (t < TILE) ? cnt[t] : 0u;
    unsigned pc = (c + 1u) & ~1u;
    if (t < TILE) sc[t] = pc;
    __syncthreads();
    #pragma unroll
    for (int ofs = 1; ofs < TILE; ofs <<= 1) {
        unsigned a = 0u;
        if (t < TILE && t >= ofs) a = sc[t - ofs];
        __syncthreads();
        if (t < TILE) sc[t] += a;
        __syncthreads();
    }
    if (t < TILE) offs[t] = sc[t] - pc;
    if (t == TILE - 1) totpad = sc[t];
    __syncthreads();

    // CSR row starts (even). nb=781,i=32 writes roff[100000]=bucket end.
    for (int i = t; i < TILE; i += 256) {
        int n = nb * TILE + i;
        if (n <= NUM_NODES) roff[n] = gs + offs[i];
    }
    if (t == 0) bend[nb] = gs + totpad;

    // dummy slot at end of odd-count rows
    if (t < TILE && (c & 1u)) ob[offs[t] + c] = make_uint2(0u, 0u);

    // place row-sorted into ob, then coalesced in-place write-back
    #pragma unroll
    for (int it = 0; it < EPT_B; it++) {
        if (rl_[it] != 0xFFFFFFFFu)
            ob[offs[rl_[it]] + rk_[it]] = pp_[it];
    }
    __syncthreads();
    unsigned tp = totpad;
    for (unsigned s = (unsigned)t; s < tp; s += 256)
        binned[gs + s] = ob[s];

    // ---- fused layer-1 dense for this bucket's nodes ----
    // 2 threads per node: thread t -> node (t&127), output half (t>>7)
    {
        int i = t & 127, h = t >> 7;
        int n = nb * TILE + i;
        if (n < NUM_NODES) {
            const float* row = (n < NUM_USERS)
                ? ue + (size_t)n * EMB
                : ie + (size_t)(n - NUM_USERS) * EMB;
            float x[EMB];
            #pragma unroll
            for (int k4 = 0; k4 < EMB / 4; k4++) {
                float4 v = reinterpret_cast<const float4*>(row)[k4];
                x[4*k4+0] = v.x; x[4*k4+1] = v.y;
                x[4*k4+2] = v.z; x[4*k4+3] = v.w;
            }
            const float4* ws4 = reinterpret_cast<const float4*>(ws1);
            float acc[16];
            #pragma unroll
            for (int jj = 0; jj < 16; jj++) {
                int j = h * 16 + jj;
                float a = bs1[j];
                #pragma unroll
                for (int k4 = 0; k4 < EMB / 4; k4++) {
                    float4 wv = ws4[j * (EMB/4) + k4];   // lane-uniform
                    a = fmaf(wv.x, x[4*k4+0], a);
                    a = fmaf(wv.y, x[4*k4+1], a);
                    a = fmaf(wv.z, x[4*k4+2], a);
                    a = fmaf(wv.w, x[4*k4+3], a);
                }
                acc[jj] = a;
            }
            uint4* o4 = reinterpret_cast<uint4*>(h1b + (size_t)n * 16 + h * 8);
            #pragma unroll
            for (int q8 = 0; q8 < 2; q8++) {
                uint4 o;
                o.x = pack2bf(acc[8*q8+0], acc[8*q8+1]);
                o.y = pack2bf(acc[8*q8+2], acc[8*q8+3]);
                o.z = pack2bf(acc[8*q8+4], acc[8*q8+5]);
                o.w = pack2bf(acc[8*q8+6], acc[8*q8+7]);
                o4[q8] = o;
            }
        }
    }
}

// ---------------------------------------------------------------------------
// CSR aggregation, 2 nodes/wave, 32-EDGE STRAIGHT-LINE COVERAGE:
// all 4 pair-loads (chunks a,b x nodes 0,1; predicated, v=0 inert) issued
// first, then all 8 H-gathers, then FMAs -> one exposed latency wall for
// 99.98% of rows (P(deg>32 | Poisson 16) = 1.7e-4). FMA order per node is
// chunk-a then chunk-b = old first-chunk-then-tail order -> bit-identical.
// LAYER1: out = relu(agg) bf16.  !LAYER1: fused layer-2 linear epilogue.
// ---------------------------------------------------------------------------
template<bool LAYER1>
__global__ __launch_bounds__(256) void k_agg32(
    const unsigned* __restrict__ roff, const unsigned* __restrict__ bend,
    const uint2* __restrict__ binned,
    const unsigned* __restrict__ H,       // bf16 table, 16 u32 per row
    unsigned* __restrict__ outb,          // LAYER1: bf16 table out
    const float* __restrict__ w2, const float* __restrict__ b2,
    float* __restrict__ oute)             // !LAYER1: final f32 emb out
{
    __shared__ float w2s[EMB * 33];   // (only used by !LAYER1; LDS not binding)
    __shared__ float bs2[EMB];
    __shared__ float gbuf[4][2][32];

    int t = threadIdx.x;
    if (!LAYER1) {
        for (int idx = t; idx < EMB * HID; idx += 256) {
            int j = idx >> 5, k = idx & 31;
            w2s[j * 33 + k] = w2[idx];
        }
        if (t < EMB) bs2[t] = b2[t];
        __syncthreads();   // once, early: all staging visible before epilogue
    }

    int wave = t >> 6;
    int lane = t & 63;
    int g = lane >> 3;          // edge group 0..7
    int q = lane & 7;           // feature quad 0..7 (uint2 = 4 bf16)
    int n0 = blockIdx.x * 8 + wave * 2;   // grid = NUM_NODES/8 exactly
    int n1 = n0 + 1;
    unsigned s0 = roff[n0];
    unsigned s1 = roff[n1];               // n0 even -> same bucket; e0 == s1
    unsigned e0 = s1;
    unsigned e1 = ((n1 & 127) == 127) ? bend[n1 >> 7] : roff[n1 + 1];

    float4 acc0 = make_float4(0.f, 0.f, 0.f, 0.f);
    float4 acc1 = make_float4(0.f, 0.f, 0.f, 0.f);
    float sv0 = 0.f, sv1 = 0.f;

    // ---- 32-edge straight-line: 4 pair loads, then 8 H-gathers ----
    unsigned k0a = s0 + 2u * (unsigned)g, k0b = k0a + 16u;
    unsigned k1a = s1 + 2u * (unsigned)g, k1b = k1a + 16u;
    u32x4 P0a = (u32x4){0u, 0u, 0u, 0u};
    u32x4 P0b = (u32x4){0u, 0u, 0u, 0u};
    u32x4 P1a = (u32x4){0u, 0u, 0u, 0u};
    u32x4 P1b = (u32x4){0u, 0u, 0u, 0u};
    // rows even-length: k<e implies both edges of the 16B load valid
    if (k0a < e0) P0a = __builtin_nontemporal_load(
        reinterpret_cast<const u32x4*>(&binned[k0a]));
    if (k0b < e0) P0b = __builtin_nontemporal_load(
        reinterpret_cast<const u32x4*>(&binned[k0b]));
    if (k1a < e1) P1a = __builtin_nontemporal_load(
        reinterpret_cast<const u32x4*>(&binned[k1a]));
    if (k1b < e1) P1b = __builtin_nontemporal_load(
        reinterpret_cast<const u32x4*>(&binned[k1b]));
    // inactive lanes gather H row 0 (broadcast line) with v=0 -> inert
    {
        uint2 hax0 = *(reinterpret_cast<const uint2*>(H + (size_t)(P0a.x & 0x1FFFFu) * 16) + q);
        uint2 haz0 = *(reinterpret_cast<const uint2*>(H + (size_t)(P0a.z & 0x1FFFFu) * 16) + q);
        uint2 hbx0 = *(reinterpret_cast<const uint2*>(H + (size_t)(P0b.x & 0x1FFFFu) * 16) + q);
        uint2 hbz0 = *(reinterpret_cast<const uint2*>(H + (size_t)(P0b.z & 0x1FFFFu) * 16) + q);
        uint2 hax1 = *(reinterpret_cast<const uint2*>(H + (size_t)(P1a.x & 0x1FFFFu) * 16) + q);
        uint2 haz1 = *(reinterpret_cast<const uint2*>(H + (size_t)(P1a.z & 0x1FFFFu) * 16) + q);
        uint2 hbx1 = *(reinterpret_cast<const uint2*>(H + (size_t)(P1b.x & 0x1FFFFu) * 16) + q);
        uint2 hbz1 = *(reinterpret_cast<const uint2*>(H + (size_t)(P1b.z & 0x1FFFFu) * 16) + q);
        float va0 = __uint_as_float(P0a.y), vb0 = __uint_as_float(P0a.w);
        float vc0 = __uint_as_float(P0b.y), vd0 = __uint_as_float(P0b.w);
        float va1 = __uint_as_float(P1a.y), vb1 = __uint_as_float(P1a.w);
        float vc1 = __uint_as_float(P1b.y), vd1 = __uint_as_float(P1b.w);
        // node 0: chunk a then chunk b (same order as old first-chunk + tail)
        acc0.x = fmaf(va0, bflo(hax0.x), acc0.x);
        acc0.y = fmaf(va0, bfhi(hax0.x), acc0.y);
        acc0.z = fmaf(va0, bflo(hax0.y), acc0.z);
        acc0.w = fmaf(va0, bfhi(hax0.y), acc0.w);
        acc0.x = fmaf(vb0, bflo(haz0.x), acc0.x);
        acc0.y = fmaf(vb0, bfhi(haz0.x), acc0.y);
        acc0.z = fmaf(vb0, bflo(haz0.y), acc0.z);
        acc0.w = fmaf(vb0, bfhi(haz0.y), acc0.w);
        acc0.x = fmaf(vc0, bflo(hbx0.x), acc0.x);
        acc0.y = fmaf(vc0, bfhi(hbx0.x), acc0.y);
        acc0.z = fmaf(vc0, bflo(hbx0.y), acc0.z);
        acc0.w = fmaf(vc0, bfhi(hbx0.y), acc0.w);
        acc0.x = fmaf(vd0, bflo(hbz0.x), acc0.x);
        acc0.y = fmaf(vd0, bfhi(hbz0.x), acc0.y);
        acc0.z = fmaf(vd0, bflo(hbz0.y), acc0.z);
        acc0.w = fmaf(vd0, bfhi(hbz0.y), acc0.w);
        // node 1
        acc1.x = fmaf(va1, bflo(hax1.x), acc1.x);
        acc1.y = fmaf(va1, bfhi(hax1.x), acc1.y);
        acc1.z = fmaf(va1, bflo(hax1.y), acc1.z);
        acc1.w = fmaf(va1, bfhi(hax1.y), acc1.w);
        acc1.x = fmaf(vb1, bflo(haz1.x), acc1.x);
        acc1.y = fmaf(vb1, bfhi(haz1.x), acc1.y);
        acc1.z = fmaf(vb1, bflo(haz1.y), acc1.z);
        acc1.w = fmaf(vb1, bfhi(haz1.y), acc1.w);
        acc1.x = fmaf(vc1, bflo(hbx1.x), acc1.x);
        acc1.y = fmaf(vc1, bfhi(hbx1.x), acc1.y);
        acc1.z = fmaf(vc1, bflo(hbx1.y), acc1.z);
        acc1.w = fmaf(vc1, bfhi(hbx1.y), acc1.w);
        acc1.x = fmaf(vd1, bflo(hbz1.x), acc1.x);
        acc1.y = fmaf(vd1, bfhi(hbz1.x), acc1.y);
        acc1.z = fmaf(vd1, bflo(hbz1.y), acc1.z);
        acc1.w = fmaf(vd1, bfhi(hbz1.y), acc1.w);
        if (!LAYER1) {
            sv0 += va0 + vb0; sv0 += vc0 + vd0;
            sv1 += va1 + vb1; sv1 += vc1 + vd1;
        }
    }
    // ---- rare tails (P(deg>32) = 1.7e-4) ----
    for (unsigned k = k0a + 32u; k < e0; k += 16u) {
        u32x4 pp = __builtin_nontemporal_load(
            reinterpret_cast<const u32x4*>(&binned[k]));
        float va = __uint_as_float(pp.y), vb = __uint_as_float(pp.w);
        uint2 ha = *(reinterpret_cast<const uint2*>(H + (size_t)(pp.x & 0x1FFFFu) * 16) + q);
        uint2 hb = *(reinterpret_cast<const uint2*>(H + (size_t)(pp.z & 0x1FFFFu) * 16) + q);
        acc0.x = fmaf(va, bflo(ha.x), acc0.x);
        acc0.y = fmaf(va, bfhi(ha.x), acc0.y);
        acc0.z = fmaf(va, bflo(ha.y), acc0.z);
        acc0.w = fmaf(va, bfhi(ha.y), acc0.w);
        acc0.x = fmaf(vb, bflo(hb.x), acc0.x);
        acc0.y = fmaf(vb, bfhi(hb.x), acc0.y);
        acc0.z = fmaf(vb, bflo(hb.y), acc0.z);
        acc0.w = fmaf(vb, bfhi(hb.y), acc0.w);
        if (!LAYER1) sv0 += va + vb;
    }
    for (unsigned k = k1a + 32u; k < e1; k += 16u) {
        u32x4 pp = __builtin_nontemporal_load(
            reinterpret_cast<const u32x4*>(&binned[k]));
        float va = __uint_as_float(pp.y), vb = __uint_as_float(pp.w);
        uint2 ha = *(reinterpret_cast<const uint2*>(H + (size_t)(pp.x & 0x1FFFFu) * 16) + q);
        uint2 hb = *(reinterpret_cast<const uint2*>(H + (size_t)(pp.z & 0x1FFFFu) * 16) + q);
        acc1.x = fmaf(va, bflo(ha.x), acc1.x);
        acc1.y = fmaf(va, bfhi(ha.x), acc1.y);
        acc1.z = fmaf(va, bflo(ha.y), acc1.z);
        acc1.w = fmaf(va, bfhi(ha.y), acc1.w);
        acc1.x = fmaf(vb, bflo(hb.x), acc1.x);
        acc1.y = fmaf(vb, bfhi(hb.x), acc1.y);
        acc1.z = fmaf(vb, bflo(hb.y), acc1.z);
        acc1.w = fmaf(vb, bfhi(hb.y), acc1.w);
        if (!LAYER1) sv1 += va + vb;
    }

    #pragma unroll
    for (int m = 8; m < 64; m <<= 1) {    // cross-group butterfly (all lanes)
        acc0.x += __shfl_xor(acc0.x, m);
        acc0.y += __shfl_xor(acc0.y, m);
        acc0.z += __shfl_xor(acc0.z, m);
        acc0.w += __shfl_xor(acc0.w, m);
        acc1.x += __shfl_xor(acc1.x, m);
        acc1.y += __shfl_xor(acc1.y, m);
        acc1.z += __shfl_xor(acc1.z, m);
        acc1.w += __shfl_xor(acc1.w, m);
        if (!LAYER1) { sv0 += __shfl_xor(sv0, m); sv1 += __shfl_xor(sv1, m); }
    }

    if (LAYER1) {
        if (g == 0) {
            acc0.x = fmaxf(acc0.x, 0.f); acc0.y = fmaxf(acc0.y, 0.f);
            acc0.z = fmaxf(acc0.z, 0.f); acc0.w = fmaxf(acc0.w, 0.f);
            acc1.x = fmaxf(acc1.x, 0.f); acc1.y = fmaxf(acc1.y, 0.f);
            acc1.z = fmaxf(acc1.z, 0.f); acc1.w = fmaxf(acc1.w, 0.f);
            u32x2 o0 = (u32x2){pack2bf(acc0.x, acc0.y), pack2bf(acc0.z, acc0.w)};
            u32x2 o1 = (u32x2){pack2bf(acc1.x, acc1.y), pack2bf(acc1.z, acc1.w)};
            __builtin_nontemporal_store(o0,
                reinterpret_cast<u32x2*>(outb + (size_t)n0 * 16) + q);
            __builtin_nontemporal_store(o1,
                reinterpret_cast<u32x2*>(outb + (size_t)n1 * 16) + q);
        }
    } else {
        if (g == 0) {
            gbuf[wave][0][q * 4 + 0] = acc0.x;
            gbuf[wave][0][q * 4 + 1] = acc0.y;
            gbuf[wave][0][q * 4 + 2] = acc0.z;
            gbuf[wave][0][q * 4 + 3] = acc0.w;
            gbuf[wave][1][q * 4 + 0] = acc1.x;
            gbuf[wave][1][q * 4 + 1] = acc1.y;
            gbuf[wave][1][q * 4 + 2] = acc1.z;
            gbuf[wave][1][q * 4 + 3] = acc1.w;
        }
        // same-wave LDS RAW: compiler inserts lgkmcnt wait; no barrier needed
        float a0 = sv0 * bs2[lane];
        float a1 = sv1 * bs2[lane];
        const float* wr = &w2s[lane * 33];   // (lane+k)%32 banking: 2-way, free
        const float* g0 = gbuf[wave][0];     // broadcast
        const float* g1 = gbuf[wave][1];
        #pragma unroll
        for (int k = 0; k < HID; k++) {
            a0 = fmaf(g0[k], wr[k], a0);
            a1 = fmaf(g1[k], wr[k], a1);
        }
        __builtin_nontemporal_store(fmaxf(a0, 0.f),
                                    &oute[(size_t)n0 * EMB + lane]);
        __builtin_nontemporal_store(fmaxf(a1, 0.f),
                                    &oute[(size_t)n1 * EMB + lane]);
    }
}

// ---------------------------------------------------------------------------
// MLP head: 32 threads per sample, 8 samples per block.
// ---------------------------------------------------------------------------
__global__ __launch_bounds__(256) void k_mlp(
    const int* __restrict__ uids, const int* __restrict__ iids,
    const float* __restrict__ uemb, const float* __restrict__ iemb,
    const float* __restrict__ p1w, const float* __restrict__ p1b,
    const float* __restrict__ p2w, const float* __restrict__ p2b,
    float* __restrict__ scores)
{
    __shared__ float w1t[2 * EMB * HID];   // [k4][j][4] packing
    __shared__ float zt[8][2 * EMB];
    __shared__ float b1s[HID];
    __shared__ float w2s[HID];

    for (int i = threadIdx.x; i < HID * 2 * EMB; i += 256) {
        int j = i >> 7;
        int k = i & 127;
        int k4 = k >> 2, c = k & 3;
        w1t[k4 * 128 + j * 4 + c] = p1w[i];
    }
    if (threadIdx.x < HID) {
        b1s[threadIdx.x] = p1b[threadIdx.x];
        w2s[threadIdx.x] = p2w[threadIdx.x];
    }
    __syncthreads();

    int lg = threadIdx.x >> 5;
    int j  = threadIdx.x & 31;
    int s  = blockIdx.x * 8 + lg;

    {
        int u  = uids[s];
        int it = iids[s];
        const float* bu = uemb + (size_t)u * EMB;
        const float* bi = iemb + (size_t)it * EMB;
        float* zs = zt[lg];
        zs[j]      = bu[j];
        zs[32 + j] = bu[32 + j];
        zs[64 + j] = bi[j];
        zs[96 + j] = bi[32 + j];
    }
    __syncthreads();

    const float*  zs = zt[lg];
    const float4* w4 = reinterpret_cast<const float4*>(w1t);
    const float4* z4 = reinterpret_cast<const float4*>(zs);
    float a = b1s[j];
    #pragma unroll
    for (int k4 = 0; k4 < 32; k4++) {
        float4 wv = w4[k4 * 32 + j];
        float4 zv = z4[k4];
        a = fmaf(wv.x, zv.x, a);
        a = fmaf(wv.y, zv.y, a);
        a = fmaf(wv.z, zv.z, a);
        a = fmaf(wv.w, zv.w, a);
    }
    a = fmaxf(a, 0.f);
    float part = a * w2s[j];
    #pragma unroll
    for (int m = 16; m >= 1; m >>= 1) part += __shfl_xor(part, m);
    if (j == 0) scores[s] = 1.f / (1.f + expf(-(part + p2b[0])));
}

// ---------------------------------------------------------------------------
extern "C" void kernel_launch(void* const* d_in, const int* in_sizes, int n_in,
                              void* d_out, int out_size, void* d_ws, size_t ws_size,
                              hipStream_t stream)
{
    const int*   user_ids = (const int*)  d_in[0];
    const int*   item_ids = (const int*)  d_in[1];
    const int*   adj_rows = (const int*)  d_in[2];
    const int*   adj_cols = (const int*)  d_in[3];
    const float* adj_vals = (const float*)d_in[4];
    const float* user_emb = (const float*)d_in[5];
    const float* item_emb = (const float*)d_in[6];
    const float* gc1_w    = (const float*)d_in[7];
    const float* gc1_b    = (const float*)d_in[8];
    const float* gc2_w    = (const float*)d_in[9];
    const float* gc2_b    = (const float*)d_in[10];
    const float* p1_w     = (const float*)d_in[11];
    const float* p1_b     = (const float*)d_in[12];
    const float* p2_w     = (const float*)d_in[13];
    const float* p2_b     = (const float*)d_in[14];

    float* out     = (float*)d_out;
    float* scores  = out;
    float* emb_out = out + BATCH;          // 100000*64 floats

    unsigned* ws_u   = (unsigned*)d_ws;
    unsigned* cur    = ws_u + WS_CUR;
    unsigned* bend   = ws_u + WS_BEND;
    unsigned* roff   = ws_u + WS_ROFF;
    uint2*    binned = (uint2*)(ws_u + WS_BINNED);
    unsigned* H1B    = ws_u + WS_H1B;
    unsigned* A1B    = ws_u + WS_A1B;

    // ---- partition + fused layer-1 linear ----
    k_initcur<<<1, 1024, 0, stream>>>(cur);
    k_partA<<<NBLK_A, 512, 0, stream>>>(adj_rows, adj_cols, adj_vals,
                                        cur, binned);
    k_partB<<<NBUCK, 256, 0, stream>>>(cur, binned, roff, bend,
                                       user_emb, item_emb, gc1_w, gc1_b, H1B);

    // ---- layer 1 aggregation (bf16 in, bf16 relu out), 8 nodes/block ----
    k_agg32<true><<<NUM_NODES / 8, 256, 0, stream>>>(
        roff, bend, binned, H1B, A1B, nullptr, nullptr, nullptr);

    // ---- layer 2 aggregation + fused linear (final embeddings) ----
    k_agg32<false><<<NUM_NODES / 8, 256, 0, stream>>>(
        roff, bend, binned, A1B, nullptr, gc2_w, gc2_b, emb_out);

    // ---- MLP head ----
    k_mlp<<<BATCH / 8, 256, 0, stream>>>(
        user_ids, item_ids, emb_out, emb_out + (size_t)NUM_USERS * EMB,
        p1_w, p1_b, p2_w, p2_b, scores);
}